// Round 2
// baseline (283.111 us; speedup 1.0000x reference)
//
#include <hip/hip_runtime.h>

#define S_DIM 2048
#define K_DIM 4096
#define O_DIM 4096
#define NNON  3968   // H - KEEPER
#define NB    31     // low-precision blocks

#define XBLK 8192    // scale_x segment blocks:  S*K/4/256
#define WBLK 16384   // scale_w segment blocks:  O*K/4/256

typedef __bf16 bf16x8 __attribute__((ext_vector_type(8)));
typedef float  f32x4  __attribute__((ext_vector_type(4)));

__device__ __forceinline__ unsigned short f2bf(float f) {
    union { float f; unsigned u; } v; v.f = f;
    unsigned r = v.u + 0x7FFFu + ((v.u >> 16) & 1u);   // round-to-nearest-even
    return (unsigned short)(r >> 16);
}

// One fused prepass launch, two block-uniform segments:
//   [0, XBLK)           A'[s,k] = bf16(x * sc_lo/hi)
//   [XBLK, XBLK+WBLK)   B'[o,k] = bf16(w * scales/keep)
__global__ __launch_bounds__(256) void prepass(const float* __restrict__ x,
                                               const float* __restrict__ sc_lo,
                                               const float* __restrict__ sc_hi,
                                               const float* __restrict__ w,
                                               const float* __restrict__ scales,
                                               const float* __restrict__ keep,
                                               unsigned short* __restrict__ A,
                                               unsigned short* __restrict__ B)
{
    const int b = blockIdx.x;
    if (b < XBLK) {
        int idx = b * 256 + threadIdx.x;           // over S*K/4, K/4 = 1024
        int s = idx >> 10;
        int k = (idx & 1023) << 2;                 // 4 elems never straddle a 128-block
        float4 v = ((const float4*)x)[idx];
        float sc = (k < NNON) ? sc_lo[s * NB + (k >> 7)] : sc_hi[s];
        ushort4 o;
        o.x = f2bf(v.x * sc); o.y = f2bf(v.y * sc);
        o.z = f2bf(v.z * sc); o.w = f2bf(v.w * sc);
        ((ushort4*)A)[idx] = o;
    } else {
        int idx = (b - XBLK) * 256 + threadIdx.x;  // over O*K/4
        int o = idx >> 10;
        int k = (idx & 1023) << 2;
        float4 v = ((const float4*)w)[idx];
        float sc = (k < NNON) ? scales[(size_t)o * NNON + ((k >> 7) << 7)] : keep[o];
        ushort4 r;
        r.x = f2bf(v.x * sc); r.y = f2bf(v.y * sc);
        r.z = f2bf(v.z * sc); r.w = f2bf(v.w * sc);
        ((ushort4*)B)[idx] = r;
    }
}

// R8: faithful m201-geometry port with split-K=2.
//   Grid 256 = 128 tiles (8 M x 16 N of 256x256) x 2 K-slices (K=2048 each),
//   so every CU holds exactly one 512-thread / 128-KB-LDS block.
//   8 waves, wave tile 128x64 (acc[8][4]) -> 0.375 KB LDS frags per MFMA.
//   Per K-tile (BK=64): 4 phases, each {ds_read subtile; stage 1 half-tile
//   (2 DMA/wave); s_barrier; setprio(1); 16 MFMA (one C-quadrant x K=64);
//   setprio(0); s_barrier}. Fragment reuse across phases:
//     p1: read Aa(i0-3)+B0(j0-1), mfma Aa*B0     p2: read B1(j2-3), mfma Aa*B1
//     p3: read Ab(i4-7),          mfma Ab*B1     p4: (no reads)     mfma Ab*B0
//   Stage schedule (slot-liveness verified against the read schedule):
//     p1: A1(u+1)   [other buffer; A1(u-1) reads done at u-1 p3]
//     p2: B0(u+2)   [this buffer;  B0(u)   reads done at p1]
//     p3: B1(u+2)   [this buffer;  B1(u)   reads done at p2]
//     p4: A0(u+2)   [this buffer;  A0(u)   reads done at p3]
//   One counted vmcnt(6) per K-tile boundary (never 0 in steady state):
//   leaves exactly tile u+2's {B0,B1,A0} (3 halves = 6 instr) in flight,
//   guarantees tile u+1 fully resident. Epilogue: unsafeAtomicAdd into a
//   memset-zeroed C (2 deterministic contributions per element).
#define BM 256
#define BN 256
#define BK 64
#define KSLICE 2048
#define NTK (KSLICE / BK)   // 32 K-tiles per block

#define GPTR(p) ((__attribute__((address_space(1))) unsigned int*)(p))
#define LPTR(p) ((__attribute__((address_space(3))) unsigned int*)(p))

__device__ __forceinline__ void vm_wait6() { asm volatile("s_waitcnt vmcnt(6)" ::: "memory"); }
__device__ __forceinline__ void vm_wait0() { asm volatile("s_waitcnt vmcnt(0)" ::: "memory"); }
__device__ __forceinline__ void wg_barrier() {
    asm volatile("" ::: "memory");
    __builtin_amdgcn_s_barrier();
    asm volatile("" ::: "memory");
}

__global__ __launch_bounds__(512, 2) void gemm_bt(const unsigned short* __restrict__ A,
                                                  const unsigned short* __restrict__ B,
                                                  float* __restrict__ C)
{
    __shared__ __align__(16) unsigned short As[2][BM * BK];   // 2 x 32 KB
    __shared__ __align__(16) unsigned short Bs[2][BN * BK];   // 2 x 32 KB

    const int tid  = threadIdx.x;
    const int wave = tid >> 6;        // 0..7
    const int lane = tid & 63;
    const int quad = lane >> 4;
    const int l16  = lane & 15;

    // XCD swizzle (bijective, 256 % 8 == 0): XCD x gets 32 consecutive swz
    // = one full M-row of 16 tiles x both K-slices (A panel L2-resident).
    const int wg   = blockIdx.x;
    const int sw   = (wg & 7) * 32 + (wg >> 3);
    const int tile = sw >> 1;                    // 0..127
    const int ksl  = sw & 1;
    const int bm = (tile >> 4) * BM;             // 8 M-tiles
    const int bn = (tile & 15) * BN;             // 16 N-tiles
    const int kbase = ksl * KSLICE;

    const int wm = (wave >> 2) * 128;            // 2 wave-rows
    const int wn = (wave & 3) * 64;              // 4 wave-cols

    // staging: per half-tile (128 rows x 64 cols) each wave issues 2 DMA of
    // 8 rows x 128 B; lane covers row r8 = lane>>3, dest chunk q8 = lane&7.
    // XOR swizzle on the *global* source column chunk (dest must stay linear):
    // slot q8 receives logical chunk q8 ^ (row&7) = q8 ^ r8.
    const int r8 = lane >> 3;
    const int q8 = lane & 7;
    const unsigned short* Ag = A + (size_t)(bm + wave * 8 + r8) * K_DIM + kbase + ((q8 ^ r8) << 3);
    const unsigned short* Bg = B + (size_t)(bn + wave * 8 + r8) * K_DIM + kbase + ((q8 ^ r8) << 3);

    f32x4 acc[8][4];
    #pragma unroll
    for (int i = 0; i < 8; ++i)
        #pragma unroll
        for (int j = 0; j < 4; ++j)
            acc[i][j] = (f32x4){0.f, 0.f, 0.f, 0.f};

    auto stageA = [&](int v, int h) {   // half h of K-tile v -> 2 DMA/thread
        unsigned short* dst = &As[v & 1][(h * 128 + wave * 8) * BK];
        const unsigned short* src = Ag + (size_t)(h * 128) * K_DIM + v * BK;
        #pragma unroll
        for (int s = 0; s < 2; ++s)
            __builtin_amdgcn_global_load_lds(GPTR(src + (size_t)(s * 64) * K_DIM),
                                             LPTR(dst + s * 64 * BK), 16, 0, 0);
    };
    auto stageB = [&](int v, int h) {
        unsigned short* dst = &Bs[v & 1][(h * 128 + wave * 8) * BK];
        const unsigned short* src = Bg + (size_t)(h * 128) * K_DIM + v * BK;
        #pragma unroll
        for (int s = 0; s < 2; ++s)
            __builtin_amdgcn_global_load_lds(GPTR(src + (size_t)(s * 64) * K_DIM),
                                             LPTR(dst + s * 64 * BK), 16, 0, 0);
    };

    // prologue: tile0 complete + first 3 halves of tile1 = 14 instr/wave.
    // vmcnt(6) -> oldest 8 (all of tile 0) landed; {B0,B1,A0}(1) in flight.
    stageA(0, 0); stageA(0, 1); stageB(0, 0); stageB(0, 1);
    stageB(1, 0); stageB(1, 1); stageA(1, 0);
    vm_wait6();
    wg_barrier();

    // reader un-swizzle: logical chunk c at row r lives in slot c ^ (r&7);
    // frag-read rows have (row&7) == (l16&7); chunk = ks*4 + quad.
    const int co0 = ((quad)     ^ (l16 & 7)) << 3;   // ks = 0
    const int co1 = ((4 + quad) ^ (l16 & 7)) << 3;   // ks = 1

    #pragma unroll 2
    for (int u = 0; u < NTK; ++u) {
        const unsigned short* asb = As[u & 1];
        const unsigned short* bsb = Bs[u & 1];
        bf16x8 Aa[2][4], Ab[2][4], B0f[2][2], B1f[2][2];

        // ---------- p1: read Aa + B0; stage A1(u+1); mfma Q(i0-3, j0-1)
        #pragma unroll
        for (int i = 0; i < 4; ++i) {
            Aa[0][i] = *(const bf16x8*)&asb[(wm + i * 16 + l16) * BK + co0];
            Aa[1][i] = *(const bf16x8*)&asb[(wm + i * 16 + l16) * BK + co1];
        }
        #pragma unroll
        for (int j = 0; j < 2; ++j) {
            B0f[0][j] = *(const bf16x8*)&bsb[(wn + j * 16 + l16) * BK + co0];
            B0f[1][j] = *(const bf16x8*)&bsb[(wn + j * 16 + l16) * BK + co1];
        }
        if (u + 1 < NTK) stageA(u + 1, 1);
        wg_barrier();
        __builtin_amdgcn_s_setprio(1);
        #pragma unroll
        for (int ks = 0; ks < 2; ++ks)
            #pragma unroll
            for (int i = 0; i < 4; ++i)
                #pragma unroll
                for (int j = 0; j < 2; ++j)
                    acc[i][j] = __builtin_amdgcn_mfma_f32_16x16x32_bf16(Aa[ks][i], B0f[ks][j],
                                                                        acc[i][j], 0, 0, 0);
        __builtin_amdgcn_s_setprio(0);
        wg_barrier();

        // ---------- p2: read B1; stage B0(u+2); mfma Q(i0-3, j2-3)
        #pragma unroll
        for (int j = 0; j < 2; ++j) {
            B1f[0][j] = *(const bf16x8*)&bsb[(wn + (j + 2) * 16 + l16) * BK + co0];
            B1f[1][j] = *(const bf16x8*)&bsb[(wn + (j + 2) * 16 + l16) * BK + co1];
        }
        if (u + 2 < NTK) stageB(u + 2, 0);
        wg_barrier();
        __builtin_amdgcn_s_setprio(1);
        #pragma unroll
        for (int ks = 0; ks < 2; ++ks)
            #pragma unroll
            for (int i = 0; i < 4; ++i)
                #pragma unroll
                for (int j = 0; j < 2; ++j)
                    acc[i][j + 2] = __builtin_amdgcn_mfma_f32_16x16x32_bf16(Aa[ks][i], B1f[ks][j],
                                                                            acc[i][j + 2], 0, 0, 0);
        __builtin_amdgcn_s_setprio(0);
        wg_barrier();

        // ---------- p3: read Ab; stage B1(u+2); mfma Q(i4-7, j2-3)
        #pragma unroll
        for (int i = 0; i < 4; ++i) {
            Ab[0][i] = *(const bf16x8*)&asb[(wm + (i + 4) * 16 + l16) * BK + co0];
            Ab[1][i] = *(const bf16x8*)&asb[(wm + (i + 4) * 16 + l16) * BK + co1];
        }
        if (u + 2 < NTK) stageB(u + 2, 1);
        wg_barrier();
        __builtin_amdgcn_s_setprio(1);
        #pragma unroll
        for (int ks = 0; ks < 2; ++ks)
            #pragma unroll
            for (int i = 0; i < 4; ++i)
                #pragma unroll
                for (int j = 0; j < 2; ++j)
                    acc[i + 4][j + 2] = __builtin_amdgcn_mfma_f32_16x16x32_bf16(Ab[ks][i], B1f[ks][j],
                                                                                acc[i + 4][j + 2], 0, 0, 0);
        __builtin_amdgcn_s_setprio(0);
        wg_barrier();

        // ---------- p4: stage A0(u+2); mfma Q(i4-7, j0-1); boundary vmcnt
        if (u + 2 < NTK) stageA(u + 2, 0);
        wg_barrier();
        __builtin_amdgcn_s_setprio(1);
        #pragma unroll
        for (int ks = 0; ks < 2; ++ks)
            #pragma unroll
            for (int i = 0; i < 4; ++i)
                #pragma unroll
                for (int j = 0; j < 2; ++j)
                    acc[i + 4][j] = __builtin_amdgcn_mfma_f32_16x16x32_bf16(Ab[ks][i], B0f[ks][j],
                                                                            acc[i + 4][j], 0, 0, 0);
        __builtin_amdgcn_s_setprio(0);
        if (u < NTK - 2)       vm_wait6();   // tile u+1 resident; u+2's 3 halves fly
        else if (u == NTK - 2) vm_wait0();   // drain last tile
        wg_barrier();
    }

    // epilogue: C/D layout (m89-verified): col = lane&15, row = quad*4 + reg.
    // Two K-slices accumulate into memset-zeroed C via HW f32 atomics.
    #pragma unroll
    for (int i = 0; i < 8; ++i)
        #pragma unroll
        for (int j = 0; j < 4; ++j) {
            const int col = bn + wn + j * 16 + l16;
            #pragma unroll
            for (int r = 0; r < 4; ++r) {
                const int row = bm + wm + i * 16 + quad * 4 + r;
                unsafeAtomicAdd(&C[(size_t)row * O_DIM + col], acc[i][j][r]);
            }
        }
}

extern "C" void kernel_launch(void* const* d_in, const int* in_sizes, int n_in,
                              void* d_out, int out_size, void* d_ws, size_t ws_size,
                              hipStream_t stream) {
    const float* x      = (const float*)d_in[0];
    const float* weight = (const float*)d_in[1];  // [O, K]
    const float* scales = (const float*)d_in[2];  // [O, NNON]
    const float* keep   = (const float*)d_in[3];  // [O, 1]
    const float* sc_lo  = (const float*)d_in[4];  // [S, NB]
    const float* sc_hi  = (const float*)d_in[5];  // [S, 1]
    // d_in[6], d_in[7] (inp_base_lo/hi) unused by reference

    // workspace: A' 16 MB @ 0, B' 32 MB @ 16 MB (needs 48 MB of d_ws)
    unsigned short* A = (unsigned short*)d_ws;
    unsigned short* B = A + (size_t)S_DIM * K_DIM;

    hipMemsetAsync(d_out, 0, (size_t)S_DIM * O_DIM * sizeof(float), stream);
    prepass<<<XBLK + WBLK, 256, 0, stream>>>(x, sc_lo, sc_hi, weight, scales, keep, A, B);

    dim3 grid(256);   // 128 tiles x 2 K-slices, XCD-swizzled in-kernel
    gemm_bt<<<grid, 512, 0, stream>>>(A, B, (float*)d_out);
}

// Round 3
// 257.634 us; speedup vs baseline: 1.0989x; 1.0989x over previous
//
#include <hip/hip_runtime.h>

#define S_DIM 2048
#define K_DIM 4096
#define O_DIM 4096
#define NNON  3968   // H - KEEPER
#define NB    31     // low-precision blocks

#define XBLK 8192    // scale_x segment blocks:  S*K/4/256
#define WBLK 16384   // scale_w segment blocks:  O*K/4/256

typedef __bf16 bf16x8 __attribute__((ext_vector_type(8)));
typedef float  f32x4  __attribute__((ext_vector_type(4)));

__device__ __forceinline__ unsigned short f2bf(float f) {
    union { float f; unsigned u; } v; v.f = f;
    unsigned r = v.u + 0x7FFFu + ((v.u >> 16) & 1u);   // round-to-nearest-even
    return (unsigned short)(r >> 16);
}

// One fused prepass launch, two block-uniform segments:
//   [0, XBLK)           A'[s,k] = bf16(x * sc_lo/hi)
//   [XBLK, XBLK+WBLK)   B'[o,k] = bf16(w * scales/keep)
__global__ __launch_bounds__(256) void prepass(const float* __restrict__ x,
                                               const float* __restrict__ sc_lo,
                                               const float* __restrict__ sc_hi,
                                               const float* __restrict__ w,
                                               const float* __restrict__ scales,
                                               const float* __restrict__ keep,
                                               unsigned short* __restrict__ A,
                                               unsigned short* __restrict__ B)
{
    const int b = blockIdx.x;
    if (b < XBLK) {
        int idx = b * 256 + threadIdx.x;           // over S*K/4, K/4 = 1024
        int s = idx >> 10;
        int k = (idx & 1023) << 2;                 // 4 elems never straddle a 128-block
        float4 v = ((const float4*)x)[idx];
        float sc = (k < NNON) ? sc_lo[s * NB + (k >> 7)] : sc_hi[s];
        ushort4 o;
        o.x = f2bf(v.x * sc); o.y = f2bf(v.y * sc);
        o.z = f2bf(v.z * sc); o.w = f2bf(v.w * sc);
        ((ushort4*)A)[idx] = o;
    } else {
        int idx = (b - XBLK) * 256 + threadIdx.x;  // over O*K/4
        int o = idx >> 10;
        int k = (idx & 1023) << 2;
        float4 v = ((const float4*)w)[idx];
        float sc = (k < NNON) ? scales[(size_t)o * NNON + ((k >> 7) << 7)] : keep[o];
        ushort4 r;
        r.x = f2bf(v.x * sc); r.y = f2bf(v.y * sc);
        r.z = f2bf(v.z * sc); r.w = f2bf(v.w * sc);
        ((ushort4*)B)[idx] = r;
    }
}

// R9: full-K 8-phase/2-K-tile schedule at BM=128 x BN=256 (grid 16x16 = 256
// WGs, no split-K -> plain stores, no memset, no atomics).
//   8 waves 1M x 8N: wave tile 128x32 (acc[8][2]); all waves share A frags.
//   LDS 96 KB: As[2][128x64] + Bs[2][256x64]; EVEN tiles always buffer 0,
//   ODD tiles buffer 1 (tiles advance by 2 per iteration -> static buffers).
//   XOR chunk swizzle (16B granule, slot = chunk ^ (row&7)) applied on the
//   global source column (R7/R8: measured 0 bank conflicts).
//   Iteration = tiles E=2i (buf0), O=2i+1 (buf1); 4 phases x {reads; stage;
//   barrier; lgkmcnt(0); setprio(1); 16 MFMA; setprio(0); [vmcnt]; barrier}:
//     p1: read E.Alo+E.B (12);  stage A(O)        ; mfma acc[0..3][*] += E
//     p2: read E.Ahi     (8);   stage B(E+2) x2   ; mfma acc[4..7][*] += E
//          end-p2 vmcnt(4): retires {B(O),A(O)} -> O resident for p3;
//          leaves B(E+2)'s 4 loads in flight.
//     p3: read O.Alo+O.B (12);  stage A(E+2)      ; mfma acc[0..3][*] += O
//     p4: read O.Ahi     (8);   stage B(O+2) x2   ; mfma acc[4..7][*] += O
//          end-p4 vmcnt(4): retires {B(E+2),A(E+2)} -> E+2 resident for
//          next p1; leaves B(O+2)'s 4 loads in flight.
//   Stage-slot safety (slab's last read -> closing barrier -> stage phase):
//     A(O)   @p1: A(O-2) reads end p4(prev), p1 is after its closing bar.
//     B(E+2) @p2: B(E) reads all in p1, done by p1 closing bar.
//     A(E+2) @p3: A(E) reads in p1+p2, done by p2 closing bar.
//     B(O+2) @p4: B(O) reads all in p3, done by p3 closing bar.
//   Tail: last iteration stages only A(O) and uses vmcnt(0) at mid.
#define BM 128
#define BN 256
#define BK 64
#define NTILES (K_DIM / BK)   // 64
#define NIT (NTILES / 2)      // 32 iterations of 2 K-tiles

#define GPTR(p) ((__attribute__((address_space(1))) unsigned int*)(p))
#define LPTR(p) ((__attribute__((address_space(3))) unsigned int*)(p))

__device__ __forceinline__ void vm_wait4() { asm volatile("s_waitcnt vmcnt(4)" ::: "memory"); }
__device__ __forceinline__ void vm_wait0() { asm volatile("s_waitcnt vmcnt(0)" ::: "memory"); }
__device__ __forceinline__ void lgkm0()    { asm volatile("s_waitcnt lgkmcnt(0)" ::: "memory"); }
__device__ __forceinline__ void wg_barrier() {
    asm volatile("" ::: "memory");
    __builtin_amdgcn_s_barrier();
    asm volatile("" ::: "memory");
}

__global__ __launch_bounds__(512, 2) void gemm_bt(const unsigned short* __restrict__ A,
                                                  const unsigned short* __restrict__ B,
                                                  float* __restrict__ C)
{
    __shared__ __align__(16) unsigned short As[2][BM * BK];   // 2 x 16 KB
    __shared__ __align__(16) unsigned short Bs[2][BN * BK];   // 2 x 32 KB

    const int tid  = threadIdx.x;
    const int wave = tid >> 6;        // 0..7
    const int lane = tid & 63;
    const int quad = lane >> 4;
    const int l16  = lane & 15;

    // XCD swizzle (bijective, 256 WGs): XCD x gets 32 consecutive sw
    // = 2 full M-rows of 16 N-tiles (A panels 16-way L2-reused).
    const int wg = blockIdx.x;
    const int sw = (wg & 7) * 32 + (wg >> 3);
    const int bm = (sw >> 4) * BM;               // 16 M-tiles
    const int bn = (sw & 15) * BN;               // 16 N-tiles

    const int wn = wave * 32;                    // wave col offset (1M x 8N)

    // staging lanes: row r8 = lane>>3, dest 16B chunk q8 = lane&7;
    // source column chunk pre-swizzled: q8 ^ (row&7) = q8 ^ r8.
    const int r8 = lane >> 3;
    const int q8 = lane & 7;
    const unsigned short* Ag = A + (size_t)(bm + wave * 8 + r8) * K_DIM + ((q8 ^ r8) << 3);
    const unsigned short* Bg = B + (size_t)(bn + wave * 8 + r8) * K_DIM + ((q8 ^ r8) << 3);

    f32x4 acc[8][2];
    #pragma unroll
    for (int ii = 0; ii < 8; ++ii)
        #pragma unroll
        for (int j = 0; j < 2; ++j)
            acc[ii][j] = (f32x4){0.f, 0.f, 0.f, 0.f};

    auto stageA = [&](int buf, int t) {   // one 128-row A slab: 2 DMA/thread
        unsigned short* dst = &As[buf][(wave * 8) * BK];
        const unsigned short* src = Ag + t * BK;
        #pragma unroll
        for (int s = 0; s < 2; ++s)
            __builtin_amdgcn_global_load_lds(GPTR(src + (size_t)(s * 64) * K_DIM),
                                             LPTR(dst + s * 64 * BK), 16, 0, 0);
    };
    auto stageB = [&](int buf, int t, int h) {   // B slab h (128 rows): 2 DMA
        unsigned short* dst = &Bs[buf][(h * 128 + wave * 8) * BK];
        const unsigned short* src = Bg + (size_t)(h * 128) * K_DIM + t * BK;
        #pragma unroll
        for (int s = 0; s < 2; ++s)
            __builtin_amdgcn_global_load_lds(GPTR(src + (size_t)(s * 64) * K_DIM),
                                             LPTR(dst + s * 64 * BK), 16, 0, 0);
    };

    // prologue: all of tile 0 (6 loads) + B of tile 1 (4 loads).
    // vmcnt(4) retires tile 0 -> resident; leaves B(1) in flight
    // (matches the steady-state entering condition; A(1) staged at p1).
    stageB(0, 0, 0); stageB(0, 0, 1); stageA(0, 0);
    stageB(1, 1, 0); stageB(1, 1, 1);
    vm_wait4();
    wg_barrier();

    // reader un-swizzle: chunk c at row r lives in slot c ^ (r&7); frag-read
    // rows have (row&7) == (l16&7); chunk = ks*4 + quad.
    const int co0 = ((quad)     ^ (l16 & 7)) << 3;   // ks = 0
    const int co1 = ((4 + quad) ^ (l16 & 7)) << 3;   // ks = 1

    #pragma unroll 1
    for (int it = 0; it < NIT; ++it) {
        const bool more = (it < NIT - 1);
        const int O  = 2 * it + 1;
        const int E2 = 2 * it + 2;
        const int O2 = 2 * it + 3;

        bf16x8 alo[2][4], ahi[2][4], bf[2][2];

        // ---------------- p1: E A-lo + E B; stage A(O)
        #pragma unroll
        for (int ii = 0; ii < 4; ++ii) {
            alo[0][ii] = *(const bf16x8*)&As[0][(ii * 16 + l16) * BK + co0];
            alo[1][ii] = *(const bf16x8*)&As[0][(ii * 16 + l16) * BK + co1];
        }
        #pragma unroll
        for (int j = 0; j < 2; ++j) {
            bf[0][j] = *(const bf16x8*)&Bs[0][(wn + j * 16 + l16) * BK + co0];
            bf[1][j] = *(const bf16x8*)&Bs[0][(wn + j * 16 + l16) * BK + co1];
        }
        stageA(1, O);
        wg_barrier(); lgkm0();
        __builtin_amdgcn_s_setprio(1);
        #pragma unroll
        for (int ks = 0; ks < 2; ++ks)
            #pragma unroll
            for (int ii = 0; ii < 4; ++ii)
                #pragma unroll
                for (int j = 0; j < 2; ++j)
                    acc[ii][j] = __builtin_amdgcn_mfma_f32_16x16x32_bf16(alo[ks][ii], bf[ks][j],
                                                                         acc[ii][j], 0, 0, 0);
        __builtin_amdgcn_s_setprio(0);
        wg_barrier();

        // ---------------- p2: E A-hi; stage B(E+2); mid vmcnt
        #pragma unroll
        for (int ii = 0; ii < 4; ++ii) {
            ahi[0][ii] = *(const bf16x8*)&As[0][((ii + 4) * 16 + l16) * BK + co0];
            ahi[1][ii] = *(const bf16x8*)&As[0][((ii + 4) * 16 + l16) * BK + co1];
        }
        if (more) { stageB(0, E2, 0); stageB(0, E2, 1); }
        wg_barrier(); lgkm0();
        __builtin_amdgcn_s_setprio(1);
        #pragma unroll
        for (int ks = 0; ks < 2; ++ks)
            #pragma unroll
            for (int ii = 0; ii < 4; ++ii)
                #pragma unroll
                for (int j = 0; j < 2; ++j)
                    acc[ii + 4][j] = __builtin_amdgcn_mfma_f32_16x16x32_bf16(ahi[ks][ii], bf[ks][j],
                                                                             acc[ii + 4][j], 0, 0, 0);
        __builtin_amdgcn_s_setprio(0);
        if (more) vm_wait4(); else vm_wait0();   // O resident after barrier
        wg_barrier();

        // ---------------- p3: O A-lo + O B; stage A(E+2)
        #pragma unroll
        for (int ii = 0; ii < 4; ++ii) {
            alo[0][ii] = *(const bf16x8*)&As[1][(ii * 16 + l16) * BK + co0];
            alo[1][ii] = *(const bf16x8*)&As[1][(ii * 16 + l16) * BK + co1];
        }
        #pragma unroll
        for (int j = 0; j < 2; ++j) {
            bf[0][j] = *(const bf16x8*)&Bs[1][(wn + j * 16 + l16) * BK + co0];
            bf[1][j] = *(const bf16x8*)&Bs[1][(wn + j * 16 + l16) * BK + co1];
        }
        if (more) stageA(0, E2);
        wg_barrier(); lgkm0();
        __builtin_amdgcn_s_setprio(1);
        #pragma unroll
        for (int ks = 0; ks < 2; ++ks)
            #pragma unroll
            for (int ii = 0; ii < 4; ++ii)
                #pragma unroll
                for (int j = 0; j < 2; ++j)
                    acc[ii][j] = __builtin_amdgcn_mfma_f32_16x16x32_bf16(alo[ks][ii], bf[ks][j],
                                                                         acc[ii][j], 0, 0, 0);
        __builtin_amdgcn_s_setprio(0);
        wg_barrier();

        // ---------------- p4: O A-hi; stage B(O+2); boundary vmcnt
        #pragma unroll
        for (int ii = 0; ii < 4; ++ii) {
            ahi[0][ii] = *(const bf16x8*)&As[1][((ii + 4) * 16 + l16) * BK + co0];
            ahi[1][ii] = *(const bf16x8*)&As[1][((ii + 4) * 16 + l16) * BK + co1];
        }
        if (more) { stageB(1, O2, 0); stageB(1, O2, 1); }
        wg_barrier(); lgkm0();
        __builtin_amdgcn_s_setprio(1);
        #pragma unroll
        for (int ks = 0; ks < 2; ++ks)
            #pragma unroll
            for (int ii = 0; ii < 4; ++ii)
                #pragma unroll
                for (int j = 0; j < 2; ++j)
                    acc[ii + 4][j] = __builtin_amdgcn_mfma_f32_16x16x32_bf16(ahi[ks][ii], bf[ks][j],
                                                                             acc[ii + 4][j], 0, 0, 0);
        __builtin_amdgcn_s_setprio(0);
        if (more) vm_wait4();                    // E+2 resident after barrier
        wg_barrier();
    }

    // epilogue: plain stores (full overwrite of C, no memset/atomics).
    // C/D layout (m89-verified): col = lane&15, row = quad*4 + reg.
    #pragma unroll
    for (int ii = 0; ii < 8; ++ii)
        #pragma unroll
        for (int j = 0; j < 2; ++j) {
            const int col = bn + wn + j * 16 + l16;
            #pragma unroll
            for (int r = 0; r < 4; ++r) {
                const int row = bm + ii * 16 + quad * 4 + r;
                C[(size_t)row * O_DIM + col] = acc[ii][j][r];
            }
        }
}

extern "C" void kernel_launch(void* const* d_in, const int* in_sizes, int n_in,
                              void* d_out, int out_size, void* d_ws, size_t ws_size,
                              hipStream_t stream) {
    const float* x      = (const float*)d_in[0];
    const float* weight = (const float*)d_in[1];  // [O, K]
    const float* scales = (const float*)d_in[2];  // [O, NNON]
    const float* keep   = (const float*)d_in[3];  // [O, 1]
    const float* sc_lo  = (const float*)d_in[4];  // [S, NB]
    const float* sc_hi  = (const float*)d_in[5];  // [S, 1]
    // d_in[6], d_in[7] (inp_base_lo/hi) unused by reference

    // workspace: A' 16 MB @ 0, B' 32 MB @ 16 MB (needs 48 MB of d_ws)
    unsigned short* A = (unsigned short*)d_ws;
    unsigned short* B = A + (size_t)S_DIM * K_DIM;

    prepass<<<XBLK + WBLK, 256, 0, stream>>>(x, sc_lo, sc_hi, weight, scales, keep, A, B);

    dim3 grid(256);   // 16 M x 16 N tiles, XCD-swizzled in-kernel
    gemm_bt<<<grid, 512, 0, stream>>>(A, B, (float*)d_out);
}

// Round 4
// 254.100 us; speedup vs baseline: 1.1142x; 1.0139x over previous
//
#include <hip/hip_runtime.h>

#define S_DIM 2048
#define K_DIM 4096
#define O_DIM 4096
#define NNON  3968   // H - KEEPER
#define NB    31     // low-precision blocks

#define XBLK 8192    // scale_x segment blocks:  S*K/4/256
#define WBLK 16384   // scale_w segment blocks:  O*K/4/256

typedef __bf16 bf16x8 __attribute__((ext_vector_type(8)));
typedef float  f32x4  __attribute__((ext_vector_type(4)));

__device__ __forceinline__ unsigned short f2bf(float f) {
    union { float f; unsigned u; } v; v.f = f;
    unsigned r = v.u + 0x7FFFu + ((v.u >> 16) & 1u);   // round-to-nearest-even
    return (unsigned short)(r >> 16);
}

// One fused prepass launch, two block-uniform segments:
//   [0, XBLK)           A'[s,k] = bf16(x * sc_lo/hi)
//   [XBLK, XBLK+WBLK)   B'[o,k] = bf16(w * scales/keep)
__global__ __launch_bounds__(256) void prepass(const float* __restrict__ x,
                                               const float* __restrict__ sc_lo,
                                               const float* __restrict__ sc_hi,
                                               const float* __restrict__ w,
                                               const float* __restrict__ scales,
                                               const float* __restrict__ keep,
                                               unsigned short* __restrict__ A,
                                               unsigned short* __restrict__ B)
{
    const int b = blockIdx.x;
    if (b < XBLK) {
        int idx = b * 256 + threadIdx.x;           // over S*K/4, K/4 = 1024
        int s = idx >> 10;
        int k = (idx & 1023) << 2;                 // 4 elems never straddle a 128-block
        float4 v = ((const float4*)x)[idx];
        float sc = (k < NNON) ? sc_lo[s * NB + (k >> 7)] : sc_hi[s];
        ushort4 o;
        o.x = f2bf(v.x * sc); o.y = f2bf(v.y * sc);
        o.z = f2bf(v.z * sc); o.w = f2bf(v.w * sc);
        ((ushort4*)A)[idx] = o;
    } else {
        int idx = (b - XBLK) * 256 + threadIdx.x;  // over O*K/4
        int o = idx >> 10;
        int k = (idx & 1023) << 2;
        float4 v = ((const float4*)w)[idx];
        float sc = (k < NNON) ? scales[(size_t)o * NNON + ((k >> 7) << 7)] : keep[o];
        ushort4 r;
        r.x = f2bf(v.x * sc); r.y = f2bf(v.y * sc);
        r.z = f2bf(v.z * sc); r.w = f2bf(v.w * sc);
        ((ushort4*)B)[idx] = r;
    }
}

// R10: split-K-within-block to fix the LDS-read-bandwidth cap.
//   Model (ds_read_b128 ~85 B/cyc/CU, DMA writes share the port): R9's 8
//   waves each re-read the full 128-row A slab -> 160KB reads/CU/K-tile vs
//   1242 MFMA cyc -> 51% cap (meas 33%). Here 8 waves = 4 N-pos x 2 K-half,
//   wave tile 128x64 at K-depth 32: reads (128+64)x32x2B = 12KB/wave ->
//   96KB + 48KB DMA = 1694 cyc vs 1242 MFMA -> 73% cap.
//   Stage/vmcnt ledger is UNCHANGED from R9 (verified, race-audited): same
//   slabs, same instr counts, same barriers. Only ds_read contents, MFMA
//   mapping, and the epilogue (partial-sum exchange via Bs) change.
//   Per K-tile per wave: 12 ds_read + 32 MFMA (K=32 -> single kslice, frag
//   chunk = kh*4+quad). Phases: p1 {af[0..3] + bf[0..3] (8 rd); 16 MFMA},
//   p2 {af[4..7] (4 rd); 16 MFMA}.
//   Epilogue: kh=1 waves send acc halves through Bs (64KB, 2 rounds, XOR'd
//   chunk slot to spread banks); kh=0 waves add and store C (plain stores).
#define BM 128
#define BN 256
#define BK 64
#define NTILES (K_DIM / BK)   // 64
#define NIT (NTILES / 2)      // 32 iterations of 2 K-tiles

#define GPTR(p) ((__attribute__((address_space(1))) unsigned int*)(p))
#define LPTR(p) ((__attribute__((address_space(3))) unsigned int*)(p))

__device__ __forceinline__ void vm_wait4() { asm volatile("s_waitcnt vmcnt(4)" ::: "memory"); }
__device__ __forceinline__ void vm_wait0() { asm volatile("s_waitcnt vmcnt(0)" ::: "memory"); }
__device__ __forceinline__ void lgkm0()    { asm volatile("s_waitcnt lgkmcnt(0)" ::: "memory"); }
__device__ __forceinline__ void wg_barrier() {
    asm volatile("" ::: "memory");
    __builtin_amdgcn_s_barrier();
    asm volatile("" ::: "memory");
}

__global__ __launch_bounds__(512, 2) void gemm_bt(const unsigned short* __restrict__ A,
                                                  const unsigned short* __restrict__ B,
                                                  float* __restrict__ C)
{
    __shared__ __align__(16) unsigned short As[2][BM * BK];   // 2 x 16 KB
    __shared__ __align__(16) unsigned short Bs[2][BN * BK];   // 2 x 32 KB

    const int tid  = threadIdx.x;
    const int wave = tid >> 6;        // 0..7
    const int lane = tid & 63;
    const int quad = lane >> 4;
    const int l16  = lane & 15;

    // XCD swizzle (bijective, 256 WGs): XCD x gets 32 consecutive sw
    // = 2 full M-rows of 16 N-tiles (A panels 16-way L2-reused).
    const int wg = blockIdx.x;
    const int sw = (wg & 7) * 32 + (wg >> 3);
    const int bm = (sw >> 4) * BM;               // 16 M-tiles
    const int bn = (sw & 15) * BN;               // 16 N-tiles

    const int np = wave >> 1;                    // N-position 0..3
    const int kh = wave & 1;                     // K-half 0..1
    const int wn = np * 64;                      // wave col offset

    // staging lanes: row r8 = lane>>3, dest 16B chunk q8 = lane&7;
    // source column chunk pre-swizzled: q8 ^ (row&7) = q8 ^ r8.
    const int r8 = lane >> 3;
    const int q8 = lane & 7;
    const unsigned short* Ag = A + (size_t)(bm + wave * 8 + r8) * K_DIM + ((q8 ^ r8) << 3);
    const unsigned short* Bg = B + (size_t)(bn + wave * 8 + r8) * K_DIM + ((q8 ^ r8) << 3);

    f32x4 acc[8][4];
    #pragma unroll
    for (int ii = 0; ii < 8; ++ii)
        #pragma unroll
        for (int j = 0; j < 4; ++j)
            acc[ii][j] = (f32x4){0.f, 0.f, 0.f, 0.f};

    auto stageA = [&](int buf, int t) {   // one 128-row A slab: 2 DMA/thread
        unsigned short* dst = &As[buf][(wave * 8) * BK];
        const unsigned short* src = Ag + t * BK;
        #pragma unroll
        for (int s = 0; s < 2; ++s)
            __builtin_amdgcn_global_load_lds(GPTR(src + (size_t)(s * 64) * K_DIM),
                                             LPTR(dst + s * 64 * BK), 16, 0, 0);
    };
    auto stageB = [&](int buf, int t, int h) {   // B slab h (128 rows): 2 DMA
        unsigned short* dst = &Bs[buf][(h * 128 + wave * 8) * BK];
        const unsigned short* src = Bg + (size_t)(h * 128) * K_DIM + t * BK;
        #pragma unroll
        for (int s = 0; s < 2; ++s)
            __builtin_amdgcn_global_load_lds(GPTR(src + (size_t)(s * 64) * K_DIM),
                                             LPTR(dst + s * 64 * BK), 16, 0, 0);
    };

    // prologue: all of tile 0 (6 loads) + B of tile 1 (4 loads).
    // vmcnt(4) retires tile 0 -> resident; leaves B(1) in flight.
    stageB(0, 0, 0); stageB(0, 0, 1); stageA(0, 0);
    stageB(1, 1, 0); stageB(1, 1, 1);
    vm_wait4();
    wg_barrier();

    // reader un-swizzle: chunk c at row r lives in slot c ^ (r&7); frag-read
    // rows have (row&7) == (l16&7); this wave's chunk = kh*4 + quad (K-half
    // kh covers elem cols [kh*32, kh*32+32), quad picks the 8-elem slice).
    const int co = (((kh << 2) + quad) ^ (l16 & 7)) << 3;

    #pragma unroll 1
    for (int it = 0; it < NIT; ++it) {
        const bool more = (it < NIT - 1);
        const int O  = 2 * it + 1;
        const int E2 = 2 * it + 2;
        const int O2 = 2 * it + 3;

        bf16x8 af[8], bf[4];

        // ---------------- p1: E A rows 0-63 + E B; stage A(O)
        #pragma unroll
        for (int ii = 0; ii < 4; ++ii)
            af[ii] = *(const bf16x8*)&As[0][(ii * 16 + l16) * BK + co];
        #pragma unroll
        for (int j = 0; j < 4; ++j)
            bf[j] = *(const bf16x8*)&Bs[0][(wn + j * 16 + l16) * BK + co];
        stageA(1, O);
        wg_barrier(); lgkm0();
        __builtin_amdgcn_s_setprio(1);
        #pragma unroll
        for (int ii = 0; ii < 4; ++ii)
            #pragma unroll
            for (int j = 0; j < 4; ++j)
                acc[ii][j] = __builtin_amdgcn_mfma_f32_16x16x32_bf16(af[ii], bf[j],
                                                                     acc[ii][j], 0, 0, 0);
        __builtin_amdgcn_s_setprio(0);
        wg_barrier();

        // ---------------- p2: E A rows 64-127; stage B(E+2); mid vmcnt
        #pragma unroll
        for (int ii = 4; ii < 8; ++ii)
            af[ii] = *(const bf16x8*)&As[0][(ii * 16 + l16) * BK + co];
        if (more) { stageB(0, E2, 0); stageB(0, E2, 1); }
        wg_barrier(); lgkm0();
        __builtin_amdgcn_s_setprio(1);
        #pragma unroll
        for (int ii = 4; ii < 8; ++ii)
            #pragma unroll
            for (int j = 0; j < 4; ++j)
                acc[ii][j] = __builtin_amdgcn_mfma_f32_16x16x32_bf16(af[ii], bf[j],
                                                                     acc[ii][j], 0, 0, 0);
        __builtin_amdgcn_s_setprio(0);
        if (more) vm_wait4(); else vm_wait0();   // O resident after barrier
        wg_barrier();

        // ---------------- p3: O A rows 0-63 + O B; stage A(E+2)
        #pragma unroll
        for (int ii = 0; ii < 4; ++ii)
            af[ii] = *(const bf16x8*)&As[1][(ii * 16 + l16) * BK + co];
        #pragma unroll
        for (int j = 0; j < 4; ++j)
            bf[j] = *(const bf16x8*)&Bs[1][(wn + j * 16 + l16) * BK + co];
        if (more) stageA(0, E2);
        wg_barrier(); lgkm0();
        __builtin_amdgcn_s_setprio(1);
        #pragma unroll
        for (int ii = 0; ii < 4; ++ii)
            #pragma unroll
            for (int j = 0; j < 4; ++j)
                acc[ii][j] = __builtin_amdgcn_mfma_f32_16x16x32_bf16(af[ii], bf[j],
                                                                     acc[ii][j], 0, 0, 0);
        __builtin_amdgcn_s_setprio(0);
        wg_barrier();

        // ---------------- p4: O A rows 64-127; stage B(O+2); boundary vmcnt
        #pragma unroll
        for (int ii = 4; ii < 8; ++ii)
            af[ii] = *(const bf16x8*)&As[1][(ii * 16 + l16) * BK + co];
        if (more) { stageB(1, O2, 0); stageB(1, O2, 1); }
        wg_barrier(); lgkm0();
        __builtin_amdgcn_s_setprio(1);
        #pragma unroll
        for (int ii = 4; ii < 8; ++ii)
            #pragma unroll
            for (int j = 0; j < 4; ++j)
                acc[ii][j] = __builtin_amdgcn_mfma_f32_16x16x32_bf16(af[ii], bf[j],
                                                                     acc[ii][j], 0, 0, 0);
        __builtin_amdgcn_s_setprio(0);
        if (more) vm_wait4();                    // E+2 resident after barrier
        wg_barrier();
    }

    // ---------------- epilogue: cross-K-half reduction through Bs (64 KB).
    // Each lane holds 128 partials (acc[8][4]); exchange 64 floats/round in
    // 2 rounds. Chunk slot XOR'd with lane&15 to spread banks (~2-way).
    {
        float* xch = (float*)&Bs[0][0];
        const int lbase = np * 4096 + lane * 64;        // float index
        #pragma unroll
        for (int round = 0; round < 2; ++round) {
            if (kh == 1) {
                #pragma unroll
                for (int ii = 0; ii < 8; ++ii)
                    #pragma unroll
                    for (int jj = 0; jj < 2; ++jj) {
                        const int c = ii * 2 + jj;
                        *(f32x4*)&xch[lbase + ((c ^ l16) << 2)] = acc[ii][round * 2 + jj];
                    }
            }
            wg_barrier();
            if (kh == 0) {
                #pragma unroll
                for (int ii = 0; ii < 8; ++ii)
                    #pragma unroll
                    for (int jj = 0; jj < 2; ++jj) {
                        const int c = ii * 2 + jj;
                        f32x4 p = *(const f32x4*)&xch[lbase + ((c ^ l16) << 2)];
                        acc[ii][round * 2 + jj] += p;
                    }
            }
            wg_barrier();
        }
    }

    // C/D layout (m89-verified): col = lane&15, row = quad*4 + reg.
    // Only kh=0 waves hold the full sums; they store the whole 128x64 tile.
    if (kh == 0) {
        #pragma unroll
        for (int ii = 0; ii < 8; ++ii)
            #pragma unroll
            for (int j = 0; j < 4; ++j) {
                const int col = bn + wn + j * 16 + l16;
                #pragma unroll
                for (int r = 0; r < 4; ++r) {
                    const int row = bm + ii * 16 + quad * 4 + r;
                    C[(size_t)row * O_DIM + col] = acc[ii][j][r];
                }
            }
    }
}

extern "C" void kernel_launch(void* const* d_in, const int* in_sizes, int n_in,
                              void* d_out, int out_size, void* d_ws, size_t ws_size,
                              hipStream_t stream) {
    const float* x      = (const float*)d_in[0];
    const float* weight = (const float*)d_in[1];  // [O, K]
    const float* scales = (const float*)d_in[2];  // [O, NNON]
    const float* keep   = (const float*)d_in[3];  // [O, 1]
    const float* sc_lo  = (const float*)d_in[4];  // [S, NB]
    const float* sc_hi  = (const float*)d_in[5];  // [S, 1]
    // d_in[6], d_in[7] (inp_base_lo/hi) unused by reference

    // workspace: A' 16 MB @ 0, B' 32 MB @ 16 MB (needs 48 MB of d_ws)
    unsigned short* A = (unsigned short*)d_ws;
    unsigned short* B = A + (size_t)S_DIM * K_DIM;

    prepass<<<XBLK + WBLK, 256, 0, stream>>>(x, sc_lo, sc_hi, weight, scales, keep, A, B);

    dim3 grid(256);   // 16 M x 16 N tiles, XCD-swizzled in-kernel
    gemm_bt<<<grid, 512, 0, stream>>>(A, B, (float*)d_out);
}